// Round 14
// baseline (147.061 us; speedup 1.0000x reference)
//
#include <hip/hip_runtime.h>
#include <math.h>
#include <stdint.h>

#define N_NODES 8192
#define D 7
#define K 32
#define QB 16                // queries per group == MFMA columns
#define NGRP (N_NODES / QB)  // 512 query groups
#define KCAP 160             // max keys per query (compile-time LDS bound)
#define DELTA 0.125f         // f16 screen error bound (validated R10-R13)

typedef unsigned long long u64;
typedef _Float16 h2 __attribute__((ext_vector_type(2)));
typedef _Float16 f16x8 __attribute__((ext_vector_type(8)));
typedef float f32x4 __attribute__((ext_vector_type(4)));
union U4H8 { uint4 u; f16x8 h; };

__device__ __forceinline__ unsigned pkh(float a, float b) {
    union { h2 h; unsigned u; } t;
    t.h[0] = (_Float16)a; t.h[1] = (_Float16)b; return t.u;
}
__device__ __forceinline__ unsigned ordu(float f) {
    unsigned u = __float_as_uint(f);
    return (u & 0x80000000u) ? ~u : (u | 0x80000000u);
}
__device__ __forceinline__ float unordu(unsigned o) {
    unsigned u = (o & 0x80000000u) ? (o & 0x7fffffffu) : ~o;
    return __uint_as_float(u);
}
// exact m = sqj - 2*dot(fi,fj); identical rounding chain everywhere.
__device__ __forceinline__ float dist_m(float4 b0, float4 b1, float sqj,
                                        float4 A, float4 B) {
    float dot = A.x * b0.x;
    dot = fmaf(A.y, b0.y, dot);
    dot = fmaf(A.z, b0.z, dot);
    dot = fmaf(A.w, b0.w, dot);
    dot = fmaf(B.x, b1.x, dot);
    dot = fmaf(B.y, b1.y, dot);
    dot = fmaf(B.z, b1.z, dot);
    return fmaf(-2.0f, dot, sqj);
}

// ---------------------------------------------------------------------------
// P: outb = clip(feat@W^T), fh = f16 [f0..f6,sq], xsq = f32 [f0..f6,sq]
// ---------------------------------------------------------------------------
__global__ __launch_bounds__(256)
void kP(const float* __restrict__ x, const float* __restrict__ W,
        float* __restrict__ outb, uint4* __restrict__ fh,
        float4* __restrict__ xsq4)
{
    int n = blockIdx.x * 256 + threadIdx.x;
    float4 v0 = *reinterpret_cast<const float4*>(x + n * 8);
    float4 v1 = *reinterpret_cast<const float4*>(x + n * 8 + 4);
    float f[D] = {v0.x, v0.y, v0.z, v0.w, v1.x, v1.y, v1.z};
    float sq = 0.f;
#pragma unroll
    for (int c = 0; c < D; ++c) sq += f[c] * f[c];
    fh[n] = make_uint4(pkh(f[0], f[1]), pkh(f[2], f[3]),
                       pkh(f[4], f[5]), pkh(f[6], sq));
    xsq4[n * 2]     = v0;
    xsq4[n * 2 + 1] = make_float4(v1.x, v1.y, v1.z, sq);
#pragma unroll
    for (int r = 0; r < D; ++r) {
        float acc = 0.f;
#pragma unroll
        for (int c = 0; c < D; ++c) acc += f[c] * W[r * D + c];
        outb[n * D + r] = fminf(fmaxf(acc, -1.f), 1.f);
    }
}

// ---------------------------------------------------------------------------
// A: (group g, half h) -> MFMA screen of 4096 j's, 64 slot-mins/query/half.
// slot (h,wave,lg,r) covers disjoint j-sets -> 128 disjoint slots per query.
// ---------------------------------------------------------------------------
__global__ __launch_bounds__(256)
void kA(const uint4* __restrict__ fh, const float4* __restrict__ xs4,
        float* __restrict__ smin)
{
    __shared__ uint4 qpk[QB];
    const int tid = threadIdx.x, lane = tid & 63, wave = tid >> 6;
    const int g = blockIdx.x >> 1, h = blockIdx.x & 1, i0 = g * QB;
    const int col = lane & 15, lg = lane >> 4;
    if (tid < QB) {
        float4 b0 = xs4[(i0 + tid) * 2], b1 = xs4[(i0 + tid) * 2 + 1];
        qpk[tid] = make_uint4(pkh(-2.f*b0.x, -2.f*b0.y), pkh(-2.f*b0.z, -2.f*b0.w),
                              pkh(-2.f*b1.x, -2.f*b1.y), pkh(-2.f*b1.z, 1.0f));
    }
    __syncthreads();
    U4H8 ub; ub.u = (lane < QB) ? qpk[lane] : make_uint4(0u,0u,0u,0u);
    const f16x8 bfrag = ub.h;
    const f32x4 z4 = {0.f, 0.f, 0.f, 0.f};
    const int t0 = h * 256 + wave * 64;

    float lm0 = INFINITY, lm1 = INFINITY, lm2 = INFINITY, lm3 = INFINITY;
#pragma unroll 4
    for (int tt = 0; tt < 64; ++tt) {
        int t = t0 + tt;
        uint4 au = make_uint4(0u,0u,0u,0u);
        if (lane < 16) au = fh[t * 16 + lane];
        U4H8 ua; ua.u = au;
        f32x4 acc = __builtin_amdgcn_mfma_f32_16x16x32_f16(ua.h, bfrag, z4, 0, 0, 0);
        lm0 = fminf(lm0, acc[0]); lm1 = fminf(lm1, acc[1]);
        lm2 = fminf(lm2, acc[2]); lm3 = fminf(lm3, acc[3]);
    }
    int base = (i0 + col) * 128 + h * 64 + wave * 16 + lg * 4;
    smin[base + 0] = lm0; smin[base + 1] = lm1;
    smin[base + 2] = lm2; smin[base + 3] = lm3;
}

// ---------------------------------------------------------------------------
// B: one wave per query: exact 34th-of-128 slot-mins -> exq/scr thresholds.
// ---------------------------------------------------------------------------
__global__ __launch_bounds__(512)
void kB(const float* __restrict__ smin, const float4* __restrict__ xs4,
        float* __restrict__ exq, float* __restrict__ scr)
{
    const int lane = threadIdx.x & 63;
    const int q = blockIdx.x * 8 + (threadIdx.x >> 6);
    unsigned ov0 = ordu(smin[q * 128 + lane]);
    unsigned ov1 = ordu(smin[q * 128 + 64 + lane]);
    unsigned lo = 0u, hi = 0xFFFFFFFFu;
    while (lo < hi) {
        unsigned mid = lo + ((hi - lo) >> 1);
        int c = __popcll(__ballot(ov0 <= mid)) + __popcll(__ballot(ov1 <= mid));
        if (c >= 34) hi = mid; else lo = mid + 1;
    }
    if (lane == 0) {
        float T  = unordu(lo);
        float sq = xs4[q * 2 + 1].w;
        exq[q] = fmaxf(T + DELTA, -sq);                 // exact keep
        scr[q] = fmaxf(T + 2.f * DELTA, -sq + DELTA);   // screen keep
    }
}

// ---------------------------------------------------------------------------
// C: (g,h) -> MFMA re-screen; survivors -> exact fp32 prune -> global keys.
// ---------------------------------------------------------------------------
__global__ __launch_bounds__(256)
void kC(const uint4* __restrict__ fh, const float4* __restrict__ xs4,
        const float* __restrict__ exq, const float* __restrict__ scr,
        int* __restrict__ cnt, u64* __restrict__ keys, int kcap)
{
    __shared__ uint4  qpk[QB];
    __shared__ float4 qf[QB][2];
    __shared__ float  scrL[QB], exqL[QB];
    const int tid = threadIdx.x, lane = tid & 63, wave = tid >> 6;
    const int g = blockIdx.x >> 1, h = blockIdx.x & 1, i0 = g * QB;
    const int col = lane & 15, lg = lane >> 4;
    if (tid < QB) {
        float4 b0 = xs4[(i0 + tid) * 2], b1 = xs4[(i0 + tid) * 2 + 1];
        qpk[tid] = make_uint4(pkh(-2.f*b0.x, -2.f*b0.y), pkh(-2.f*b0.z, -2.f*b0.w),
                              pkh(-2.f*b1.x, -2.f*b1.y), pkh(-2.f*b1.z, 1.0f));
        qf[tid][0] = b0; qf[tid][1] = b1;
        scrL[tid] = scr[i0 + tid]; exqL[tid] = exq[i0 + tid];
    }
    __syncthreads();
    U4H8 ub; ub.u = (lane < QB) ? qpk[lane] : make_uint4(0u,0u,0u,0u);
    const f16x8 bfrag = ub.h;
    const f32x4 z4 = {0.f, 0.f, 0.f, 0.f};
    const int t0 = h * 256 + wave * 64;
    const float myscr = scrL[col];

#pragma unroll 4
    for (int tt = 0; tt < 64; ++tt) {
        int t = t0 + tt;
        uint4 au = make_uint4(0u,0u,0u,0u);
        if (lane < 16) au = fh[t * 16 + lane];
        U4H8 ua; ua.u = au;
        f32x4 acc = __builtin_amdgcn_mfma_f32_16x16x32_f16(ua.h, bfrag, z4, 0, 0, 0);
        float mn = fminf(fminf(acc[0], acc[1]), fminf(acc[2], acc[3]));
        if (mn <= myscr) {
#pragma unroll
            for (int r = 0; r < 4; ++r) {
                if (acc[r] <= myscr) {
                    int j = t * 16 + lg * 4 + r;
                    float4 b0 = xs4[j * 2], b1 = xs4[j * 2 + 1];
                    float4 A = qf[col][0], Bv = qf[col][1];
                    float m = dist_m(b0, b1, b1.w, A, Bv);
                    if (m <= exqL[col] && j != i0 + col) {
                        float d2c = fmaxf(Bv.w + m, 0.f);
                        u64 key = ((u64)__float_as_uint(d2c) << 32) | (unsigned)j;
                        int q = i0 + col;
                        int p = atomicAdd(&cnt[q], 1);
                        if (p < kcap) keys[(size_t)q * kcap + p] = key;
                    }
                }
            }
        }
    }
}

// ---------------------------------------------------------------------------
// D: one wave per query, NO barriers: stage keys -> rank-by-count -> attention.
// Bad count -> wave-private exact fallback (sound, rare).
// ---------------------------------------------------------------------------
__global__ __launch_bounds__(512)
void kD(const float* __restrict__ x, const float4* __restrict__ xs4,
        const float* __restrict__ outb, const float* __restrict__ aw,
        const int* __restrict__ cnt, const u64* __restrict__ keys, int kcap,
        float* __restrict__ dout)
{
    __shared__ u64 kst[8][KCAP];
    __shared__ int nbrL[8][K];
    const int lane = threadIdx.x & 63, wave = threadIdx.x >> 6;
    const int q = blockIdx.x * 8 + wave;

    int M = cnt[q];
    if (M >= K && M <= kcap) {
        for (int p = lane; p < M; p += 64)
            kst[wave][p] = keys[(size_t)q * kcap + p];
    } else {
        // ---- wave-private exact fallback ----
        float4 A = xs4[q * 2], Bv = xs4[q * 2 + 1];
        u64 mink = ~0ull;
#pragma unroll 2
        for (int c = 0; c < 128; ++c) {
            int j = c * 64 + lane;
            float4 b0 = xs4[j * 2], b1 = xs4[j * 2 + 1];
            float m = dist_m(b0, b1, b1.w, A, Bv);
            float d2c = fmaxf(Bv.w + m, 0.f);
            u64 key = ((u64)__float_as_uint(d2c) << 32) | (unsigned)j;
            if (j != q) mink = (key < mink) ? key : mink;
        }
        // exact 33rd-smallest of 64 lane-min keys (disjoint j per lane)
        u64 lo = 0ull, hi = ~0ull;
        while (lo < hi) {
            u64 mid = lo + ((hi - lo) >> 1);
            int c = __popcll(__ballot(mink <= mid));
            if (c >= 33) hi = mid; else lo = mid + 1;
        }
        int base = 0;
#pragma unroll 2
        for (int c = 0; c < 128; ++c) {
            int j = c * 64 + lane;
            float4 b0 = xs4[j * 2], b1 = xs4[j * 2 + 1];
            float m = dist_m(b0, b1, b1.w, A, Bv);
            float d2c = fmaxf(Bv.w + m, 0.f);
            u64 key = ((u64)__float_as_uint(d2c) << 32) | (unsigned)j;
            bool in = (j != q) && (key <= lo);
            u64 mk = __ballot(in);
            int px = __popcll(mk & ((1ull << lane) - 1ull));
            if (in && base + px < KCAP) kst[wave][base + px] = key;
            base += (int)__popcll(mk);
        }
        M = (base > KCAP) ? KCAP : base;
    }

    // ---- rank-by-count (wave-private; keys unique) ----
#pragma unroll
    for (int s = 0; s < (KCAP + 63) / 64; ++s) {
        int p = s * 64 + lane;
        if (p < M) {
            u64 my = kst[wave][p];
            int rank = 0;
            for (int m = 0; m < M; ++m)
                rank += (kst[wave][m] < my) ? 1 : 0;
            if (rank < K) nbrL[wave][rank] = (int)(my & 0xffffffffu);
        }
    }

    // ---- attention epilogue (lanes 0..31) ----
    if (lane < K) {
        int nk = nbrL[wave][lane];
        float s = 0.f;
#pragma unroll
        for (int c = 0; c < D; ++c) s += outb[q * D + c] * aw[c];
        float xp[D + 1];
#pragma unroll
        for (int c = 0; c < D; ++c) {
            float on = outb[nk * D + c];
            xp[c] = on;
            s += on * aw[D + c];
        }
        xp[D] = x[nk * 8 + 7];

        float mx = s;
#pragma unroll
        for (int off = 16; off > 0; off >>= 1) mx = fmaxf(mx, __shfl_xor(mx, off, 32));
        float e = expf(s - mx);
        float sum = e;
#pragma unroll
        for (int off = 16; off > 0; off >>= 1) sum += __shfl_xor(sum, off, 32);
        float att = e / sum;

        float agg[D + 1];
#pragma unroll
        for (int dd = 0; dd < D + 1; ++dd) {
            float v = att * xp[dd];
#pragma unroll
            for (int off = 16; off > 0; off >>= 1) v += __shfl_xor(v, off, 32);
            agg[dd] = v;
        }

        if (lane < D) {
            float o = outb[q * D + lane];
            dout[q * 15 + lane] = o;
            dout[N_NODES * 15 + q * 15 + lane] = o;
        }
        if (lane < D + 1) {
            float av_ = agg[0];
#pragma unroll
            for (int dd = 1; dd < D + 1; ++dd) av_ = (lane == dd) ? agg[dd] : av_;
            dout[q * 15 + D + lane] = av_;
            dout[N_NODES * 15 + q * 15 + D + lane] = av_;
        }
        if (q == N_NODES - 1) dout[2 * N_NODES * 15 + lane] = att;
    }
}

extern "C" void kernel_launch(void* const* d_in, const int* in_sizes, int n_in,
                              void* d_out, int out_size, void* d_ws, size_t ws_size,
                              hipStream_t stream) {
    (void)in_sizes; (void)n_in; (void)out_size;
    const float* x = (const float*)d_in[0];
    const float* W = (const float*)d_in[1];
    const float* a = (const float*)d_in[2];
    float* out = (float*)d_out;

    size_t off = 0;
    auto alloc = [&](size_t bytes) {
        void* p = (char*)d_ws + off;
        off += (bytes + 255) & ~(size_t)255;
        return p;
    };
    float*  outb = (float*) alloc(N_NODES * D * 4);
    uint4*  fh   = (uint4*) alloc(N_NODES * 16);
    float4* xsq  = (float4*)alloc(N_NODES * 32);
    float*  smin = (float*) alloc((size_t)N_NODES * 128 * 4);
    float*  exq  = (float*) alloc(N_NODES * 4);
    float*  scr  = (float*) alloc(N_NODES * 4);
    int*    cnt  = (int*)   alloc(N_NODES * 4);
    size_t rem = (ws_size > off) ? (ws_size - off) : 0;
    int kcap = (int)((rem / 8) / N_NODES);
    if (kcap > KCAP) kcap = KCAP;
    if (kcap < 48)   kcap = 48;          // degraded but correct (fallback path)
    u64* keys = (u64*)alloc((size_t)N_NODES * kcap * 8);

    hipMemsetAsync(cnt, 0, N_NODES * 4, stream);
    hipLaunchKernelGGL(kP, dim3(N_NODES / 256), dim3(256), 0, stream,
                       x, W, outb, fh, xsq);
    hipLaunchKernelGGL(kA, dim3(NGRP * 2), dim3(256), 0, stream, fh, xsq, smin);
    hipLaunchKernelGGL(kB, dim3(N_NODES / 8), dim3(512), 0, stream,
                       smin, xsq, exq, scr);
    hipLaunchKernelGGL(kC, dim3(NGRP * 2), dim3(256), 0, stream,
                       fh, xsq, exq, scr, cnt, keys, kcap);
    hipLaunchKernelGGL(kD, dim3(N_NODES / 8), dim3(512), 0, stream,
                       x, xsq, outb, a, cnt, keys, kcap, out);
}

// Round 15
// 135.524 us; speedup vs baseline: 1.0851x; 1.0851x over previous
//
#include <hip/hip_runtime.h>
#include <math.h>
#include <stdint.h>

#define N_NODES 8192
#define D 7
#define K 32
#define QB 16                // queries per group == MFMA columns
#define NGRP (N_NODES / QB)  // 512 query groups
#define BCAP 256             // per-block (per-half) survivor cap per query
#define GCAP 384             // global screen-survivor cap per query
#define KCAP 192             // exact-key cap per query (kD LDS)
#define DELTA 0.125f         // f16 screen error bound (validated R10-R14)

typedef unsigned long long u64;
typedef _Float16 h2 __attribute__((ext_vector_type(2)));
typedef _Float16 f16x8 __attribute__((ext_vector_type(8)));
typedef float f32x4 __attribute__((ext_vector_type(4)));
union U4H8 { uint4 u; f16x8 h; };

__device__ __forceinline__ unsigned pkh(float a, float b) {
    union { h2 h; unsigned u; } t;
    t.h[0] = (_Float16)a; t.h[1] = (_Float16)b; return t.u;
}
__device__ __forceinline__ unsigned ordu(float f) {
    unsigned u = __float_as_uint(f);
    return (u & 0x80000000u) ? ~u : (u | 0x80000000u);
}
__device__ __forceinline__ float unordu(unsigned o) {
    unsigned u = (o & 0x80000000u) ? (o & 0x7fffffffu) : ~o;
    return __uint_as_float(u);
}
// exact m = sqj - 2*dot(fi,fj); identical rounding chain everywhere.
__device__ __forceinline__ float dist_m(float4 b0, float4 b1, float sqj,
                                        float4 A, float4 B) {
    float dot = A.x * b0.x;
    dot = fmaf(A.y, b0.y, dot);
    dot = fmaf(A.z, b0.z, dot);
    dot = fmaf(A.w, b0.w, dot);
    dot = fmaf(B.x, b1.x, dot);
    dot = fmaf(B.y, b1.y, dot);
    dot = fmaf(B.z, b1.z, dot);
    return fmaf(-2.0f, dot, sqj);
}

// ---------------------------------------------------------------------------
// P: outb = clip(feat@W^T), fh = f16 [f0..f6,sq], xsq = f32 [f0..f6,sq]
// ---------------------------------------------------------------------------
__global__ __launch_bounds__(256)
void kP(const float* __restrict__ x, const float* __restrict__ W,
        float* __restrict__ outb, uint4* __restrict__ fh,
        float4* __restrict__ xsq4)
{
    int n = blockIdx.x * 256 + threadIdx.x;
    float4 v0 = *reinterpret_cast<const float4*>(x + n * 8);
    float4 v1 = *reinterpret_cast<const float4*>(x + n * 8 + 4);
    float f[D] = {v0.x, v0.y, v0.z, v0.w, v1.x, v1.y, v1.z};
    float sq = 0.f;
#pragma unroll
    for (int c = 0; c < D; ++c) sq += f[c] * f[c];
    fh[n] = make_uint4(pkh(f[0], f[1]), pkh(f[2], f[3]),
                       pkh(f[4], f[5]), pkh(f[6], sq));
    xsq4[n * 2]     = v0;
    xsq4[n * 2 + 1] = make_float4(v1.x, v1.y, v1.z, sq);
#pragma unroll
    for (int r = 0; r < D; ++r) {
        float acc = 0.f;
#pragma unroll
        for (int c = 0; c < D; ++c) acc += f[c] * W[r * D + c];
        outb[n * D + r] = fminf(fmaxf(acc, -1.f), 1.f);
    }
}

// ---------------------------------------------------------------------------
// A: (group g, half h) -> MFMA screen of 4096 j's, 64 slot-mins/query/half.
// ---------------------------------------------------------------------------
__global__ __launch_bounds__(256)
void kA(const uint4* __restrict__ fh, const float4* __restrict__ xs4,
        float* __restrict__ smin)
{
    __shared__ uint4 qpk[QB];
    const int tid = threadIdx.x, lane = tid & 63, wave = tid >> 6;
    const int g = blockIdx.x >> 1, h = blockIdx.x & 1, i0 = g * QB;
    const int col = lane & 15, lg = lane >> 4;
    if (tid < QB) {
        float4 b0 = xs4[(i0 + tid) * 2], b1 = xs4[(i0 + tid) * 2 + 1];
        qpk[tid] = make_uint4(pkh(-2.f*b0.x, -2.f*b0.y), pkh(-2.f*b0.z, -2.f*b0.w),
                              pkh(-2.f*b1.x, -2.f*b1.y), pkh(-2.f*b1.z, 1.0f));
    }
    __syncthreads();
    U4H8 ub; ub.u = (lane < QB) ? qpk[lane] : make_uint4(0u,0u,0u,0u);
    const f16x8 bfrag = ub.h;
    const f32x4 z4 = {0.f, 0.f, 0.f, 0.f};
    const int t0 = h * 256 + wave * 64;

    float lm0 = INFINITY, lm1 = INFINITY, lm2 = INFINITY, lm3 = INFINITY;
#pragma unroll 4
    for (int tt = 0; tt < 64; ++tt) {
        int t = t0 + tt;
        uint4 au = make_uint4(0u,0u,0u,0u);
        if (lane < 16) au = fh[t * 16 + lane];
        U4H8 ua; ua.u = au;
        f32x4 acc = __builtin_amdgcn_mfma_f32_16x16x32_f16(ua.h, bfrag, z4, 0, 0, 0);
        lm0 = fminf(lm0, acc[0]); lm1 = fminf(lm1, acc[1]);
        lm2 = fminf(lm2, acc[2]); lm3 = fminf(lm3, acc[3]);
    }
    int base = (i0 + col) * 128 + h * 64 + wave * 16 + lg * 4;
    smin[base + 0] = lm0; smin[base + 1] = lm1;
    smin[base + 2] = lm2; smin[base + 3] = lm3;
}

// ---------------------------------------------------------------------------
// B: one wave per query: exact 34th-of-128 slot-mins -> exq/scr thresholds.
// >=34 disjoint slots <= T -> >=34 distinct j (>=33 non-diag) screen <= T
// -> exact 32nd <= T+DELTA; any true top-32 member's screen <= T+2*DELTA.
// ---------------------------------------------------------------------------
__global__ __launch_bounds__(512)
void kB(const float* __restrict__ smin, const float4* __restrict__ xs4,
        float* __restrict__ exq, float* __restrict__ scr)
{
    const int lane = threadIdx.x & 63;
    const int q = blockIdx.x * 8 + (threadIdx.x >> 6);
    unsigned ov0 = ordu(smin[q * 128 + lane]);
    unsigned ov1 = ordu(smin[q * 128 + 64 + lane]);
    unsigned lo = 0u, hi = 0xFFFFFFFFu;
    while (lo < hi) {
        unsigned mid = lo + ((hi - lo) >> 1);
        int c = __popcll(__ballot(ov0 <= mid)) + __popcll(__ballot(ov1 <= mid));
        if (c >= 34) hi = mid; else lo = mid + 1;
    }
    if (lane == 0) {
        float T  = unordu(lo);
        float sq = xs4[q * 2 + 1].w;
        exq[q] = fmaxf(T + DELTA, -sq);                 // exact keep
        scr[q] = fmaxf(T + 2.f * DELTA, -sq + DELTA);   // screen keep
    }
}

// ---------------------------------------------------------------------------
// C: (g,h) -> MFMA re-screen; survivors -> LDS lists -> one flush per query.
// NO per-survivor global traffic. Overflow poisons cnt -> kD fallback.
// ---------------------------------------------------------------------------
__global__ __launch_bounds__(256)
void kC(const uint4* __restrict__ fh, const float4* __restrict__ xs4,
        const float* __restrict__ scr, int* __restrict__ cnt,
        unsigned short* __restrict__ sj)
{
    __shared__ uint4 qpk[QB];
    __shared__ float scrL[QB];
    __shared__ unsigned short ent[QB][BCAP];   // 8 KB
    __shared__ int lcnt[QB];
    const int tid = threadIdx.x, lane = tid & 63, wave = tid >> 6;
    const int g = blockIdx.x >> 1, h = blockIdx.x & 1, i0 = g * QB;
    const int col = lane & 15, lg = lane >> 4;
    if (tid < QB) {
        float4 b0 = xs4[(i0 + tid) * 2], b1 = xs4[(i0 + tid) * 2 + 1];
        qpk[tid] = make_uint4(pkh(-2.f*b0.x, -2.f*b0.y), pkh(-2.f*b0.z, -2.f*b0.w),
                              pkh(-2.f*b1.x, -2.f*b1.y), pkh(-2.f*b1.z, 1.0f));
        scrL[tid] = scr[i0 + tid];
        lcnt[tid] = 0;
    }
    __syncthreads();
    U4H8 ub; ub.u = (lane < QB) ? qpk[lane] : make_uint4(0u,0u,0u,0u);
    const f16x8 bfrag = ub.h;
    const f32x4 z4 = {0.f, 0.f, 0.f, 0.f};
    const int t0 = h * 256 + wave * 64;
    const float myscr = scrL[col];

#pragma unroll 4
    for (int tt = 0; tt < 64; ++tt) {
        int t = t0 + tt;
        uint4 au = make_uint4(0u,0u,0u,0u);
        if (lane < 16) au = fh[t * 16 + lane];
        U4H8 ua; ua.u = au;
        f32x4 acc = __builtin_amdgcn_mfma_f32_16x16x32_f16(ua.h, bfrag, z4, 0, 0, 0);
        float mn = fminf(fminf(acc[0], acc[1]), fminf(acc[2], acc[3]));
        if (mn <= myscr) {
#pragma unroll
            for (int r = 0; r < 4; ++r) {
                if (acc[r] <= myscr) {
                    int p = atomicAdd(&lcnt[col], 1);   // LDS atomic (~cheap)
                    if (p < BCAP)
                        ent[col][p] = (unsigned short)(t * 16 + lg * 4 + r);
                }
            }
        }
    }
    __syncthreads();

    // flush: wave w -> queries w, w+8. One global atomic per query per block.
#pragma unroll
    for (int hh = 0; hh < 2; ++hh) {
        const int lq = wave + hh * 8;
        const int q  = i0 + lq;
        int n = lcnt[lq];
        int add = (n > BCAP) ? 1000000 : n;    // poison on local overflow
        if (n > BCAP) n = BCAP;
        int base = 0;
        if (lane == 0) base = atomicAdd(&cnt[q], add);
        base = __shfl(base, 0);
        for (int p = lane; p < n; p += 64) {
            int gp = base + p;
            if (gp < GCAP) sj[(size_t)q * GCAP + gp] = ent[lq][p];
        }
    }
}

// ---------------------------------------------------------------------------
// D: one wave per query, NO barriers: exact fp32 prune of screen survivors
// -> wave-private keys -> rank-by-count -> attention. Fallback if counts bad.
// ---------------------------------------------------------------------------
__global__ __launch_bounds__(512)
void kD(const float* __restrict__ x, const float4* __restrict__ xs4,
        const float* __restrict__ outb, const float* __restrict__ aw,
        const float* __restrict__ exq, const int* __restrict__ cnt,
        const unsigned short* __restrict__ sj, float* __restrict__ dout)
{
    __shared__ u64 kst[8][KCAP];               // 12 KB
    __shared__ int nbrL[8][K];
    const int lane = threadIdx.x & 63, wave = threadIdx.x >> 6;
    const int q = blockIdx.x * 8 + wave;

    const float4 A = xs4[q * 2];
    float4 Bv = xs4[q * 2 + 1];                // .w = sq_i
    int M = cnt[q];
    int m2 = 0;
    bool ok = (M >= K && M <= GCAP);
    if (ok) {
        const float thr = exq[q];
        for (int p0 = 0; p0 < M; p0 += 64) {
            int p = p0 + lane;
            bool keep = false; u64 key = 0;
            if (p < M) {
                int j = sj[(size_t)q * GCAP + p];
                float4 b0 = xs4[j * 2], b1 = xs4[j * 2 + 1];
                float m = dist_m(b0, b1, b1.w, A, Bv);
                if (m <= thr && j != q) {
                    float d2c = fmaxf(Bv.w + m, 0.f);
                    key = ((u64)__float_as_uint(d2c) << 32) | (unsigned)j;
                    keep = true;
                }
            }
            u64 mk = __ballot(keep);
            int px = __popcll(mk & ((1ull << lane) - 1ull));
            if (keep && m2 + px < KCAP) kst[wave][m2 + px] = key;
            m2 += (int)__popcll(mk);
        }
        if (m2 < K || m2 > KCAP) ok = false;
    }
    if (!ok) {
        // ---- wave-private exact fallback (sound; rare) ----
        u64 mink = ~0ull;
#pragma unroll 2
        for (int c = 0; c < 128; ++c) {
            int j = c * 64 + lane;
            float4 b0 = xs4[j * 2], b1 = xs4[j * 2 + 1];
            float m = dist_m(b0, b1, b1.w, A, Bv);
            float d2c = fmaxf(Bv.w + m, 0.f);
            u64 key = ((u64)__float_as_uint(d2c) << 32) | (unsigned)j;
            if (j != q) mink = (key < mink) ? key : mink;
        }
        u64 lo = 0ull, hi = ~0ull;
        while (lo < hi) {                      // exact 33rd of 64 lane-mins
            u64 mid = lo + ((hi - lo) >> 1);
            int c = __popcll(__ballot(mink <= mid));
            if (c >= 33) hi = mid; else lo = mid + 1;
        }
        int base = 0;
#pragma unroll 2
        for (int c = 0; c < 128; ++c) {
            int j = c * 64 + lane;
            float4 b0 = xs4[j * 2], b1 = xs4[j * 2 + 1];
            float m = dist_m(b0, b1, b1.w, A, Bv);
            float d2c = fmaxf(Bv.w + m, 0.f);
            u64 key = ((u64)__float_as_uint(d2c) << 32) | (unsigned)j;
            bool in = (j != q) && (key <= lo);
            u64 mk = __ballot(in);
            int px = __popcll(mk & ((1ull << lane) - 1ull));
            if (in && base + px < KCAP) kst[wave][base + px] = key;
            base += (int)__popcll(mk);
        }
        m2 = (base > KCAP) ? KCAP : base;
    }

    // ---- rank-by-count (wave-private; keys unique) ----
#pragma unroll
    for (int s = 0; s < (KCAP + 63) / 64; ++s) {
        int p = s * 64 + lane;
        if (p < m2) {
            u64 my = kst[wave][p];
            int rank = 0;
            for (int m = 0; m < m2; ++m)
                rank += (kst[wave][m] < my) ? 1 : 0;
            if (rank < K) nbrL[wave][rank] = (int)(my & 0xffffffffu);
        }
    }

    // ---- attention epilogue (lanes 0..31) ----
    if (lane < K) {
        int nk = nbrL[wave][lane];
        float s = 0.f;
#pragma unroll
        for (int c = 0; c < D; ++c) s += outb[q * D + c] * aw[c];
        float xp[D + 1];
#pragma unroll
        for (int c = 0; c < D; ++c) {
            float on = outb[nk * D + c];
            xp[c] = on;
            s += on * aw[D + c];
        }
        xp[D] = x[nk * 8 + 7];

        float mx = s;
#pragma unroll
        for (int off = 16; off > 0; off >>= 1) mx = fmaxf(mx, __shfl_xor(mx, off, 32));
        float e = expf(s - mx);
        float sum = e;
#pragma unroll
        for (int off = 16; off > 0; off >>= 1) sum += __shfl_xor(sum, off, 32);
        float att = e / sum;

        float agg[D + 1];
#pragma unroll
        for (int dd = 0; dd < D + 1; ++dd) {
            float v = att * xp[dd];
#pragma unroll
            for (int off = 16; off > 0; off >>= 1) v += __shfl_xor(v, off, 32);
            agg[dd] = v;
        }

        if (lane < D) {
            float o = outb[q * D + lane];
            dout[q * 15 + lane] = o;
            dout[N_NODES * 15 + q * 15 + lane] = o;
        }
        if (lane < D + 1) {
            float av_ = agg[0];
#pragma unroll
            for (int dd = 1; dd < D + 1; ++dd) av_ = (lane == dd) ? agg[dd] : av_;
            dout[q * 15 + D + lane] = av_;
            dout[N_NODES * 15 + q * 15 + D + lane] = av_;
        }
        if (q == N_NODES - 1) dout[2 * N_NODES * 15 + lane] = att;
    }
}

extern "C" void kernel_launch(void* const* d_in, const int* in_sizes, int n_in,
                              void* d_out, int out_size, void* d_ws, size_t ws_size,
                              hipStream_t stream) {
    (void)in_sizes; (void)n_in; (void)out_size; (void)ws_size;
    const float* x = (const float*)d_in[0];
    const float* W = (const float*)d_in[1];
    const float* a = (const float*)d_in[2];
    float* out = (float*)d_out;

    size_t off = 0;
    auto alloc = [&](size_t bytes) {
        void* p = (char*)d_ws + off;
        off += (bytes + 255) & ~(size_t)255;
        return p;
    };
    float*  outb = (float*) alloc(N_NODES * D * 4);
    uint4*  fh   = (uint4*) alloc(N_NODES * 16);
    float4* xsq  = (float4*)alloc(N_NODES * 32);
    float*  smin = (float*) alloc((size_t)N_NODES * 128 * 4);
    float*  exq  = (float*) alloc(N_NODES * 4);
    float*  scr  = (float*) alloc(N_NODES * 4);
    int*    cnt  = (int*)   alloc(N_NODES * 4);
    unsigned short* sj = (unsigned short*)alloc((size_t)N_NODES * GCAP * 2);

    hipMemsetAsync(cnt, 0, N_NODES * 4, stream);
    hipLaunchKernelGGL(kP, dim3(N_NODES / 256), dim3(256), 0, stream,
                       x, W, outb, fh, xsq);
    hipLaunchKernelGGL(kA, dim3(NGRP * 2), dim3(256), 0, stream, fh, xsq, smin);
    hipLaunchKernelGGL(kB, dim3(N_NODES / 8), dim3(512), 0, stream,
                       smin, xsq, exq, scr);
    hipLaunchKernelGGL(kC, dim3(NGRP * 2), dim3(256), 0, stream,
                       fh, xsq, scr, cnt, sj);
    hipLaunchKernelGGL(kD, dim3(N_NODES / 8), dim3(512), 0, stream,
                       x, xsq, outb, a, exq, cnt, sj, out);
}

// Round 17
// 92.758 us; speedup vs baseline: 1.5854x; 1.4610x over previous
//
#include <hip/hip_runtime.h>
#include <math.h>
#include <stdint.h>

#define N_NODES 8192
#define D 7
#define K 32
#define NT 512
#define QB 16                // queries per block == MFMA columns (all real)
#define CPT (N_NODES / NT)
#define TPW 64               // tiles per wave, full pass
#define SCAP 320             // screen-survivor capacity per query
#define ECAP2 256            // exact-pruned rank capacity per query
#define DELTA 0.125f         // f16 screen error bound (analytic <= ~0.09)

typedef unsigned long long u64;
typedef _Float16 h2 __attribute__((ext_vector_type(2)));
typedef _Float16 f16x8 __attribute__((ext_vector_type(8)));
typedef float f32x4 __attribute__((ext_vector_type(4)));
union U4H8 { uint4 u; f16x8 h; };

__device__ __forceinline__ unsigned pkh(float a, float b) {
    union { h2 h; unsigned u; } t;
    t.h[0] = (_Float16)a; t.h[1] = (_Float16)b; return t.u;
}
// order-preserving float<->uint (total order)
__device__ __forceinline__ unsigned ordu(float f) {
    unsigned u = __float_as_uint(f);
    return (u & 0x80000000u) ? ~u : (u | 0x80000000u);
}
__device__ __forceinline__ float unordu(unsigned o) {
    unsigned u = (o & 0x80000000u) ? (o & 0x7fffffffu) : ~o;
    return __uint_as_float(u);
}

// exact m = sqj - 2*dot(fi, fj); identical rounding chain everywhere.
__device__ __forceinline__ float dist_m(float4 b0, float4 b1, float sqj,
                                        float4 A, float4 B) {
    float dot = A.x * b0.x;
    dot = fmaf(A.y, b0.y, dot);
    dot = fmaf(A.z, b0.z, dot);
    dot = fmaf(A.w, b0.w, dot);
    dot = fmaf(B.x, b1.x, dot);
    dot = fmaf(B.y, b1.y, dot);
    dot = fmaf(B.z, b1.z, dot);
    return fmaf(-2.0f, dot, sqj);
}

// ---------------------------------------------------------------------------
// Kernel 1: outb = clip(feat @ W^T), fh = f16 [f0..f6,sq] (16 B/node),
//           xsq = f32 [f0..f6, sq] (32 B/node).
// ---------------------------------------------------------------------------
__global__ __launch_bounds__(256)
void precompute_kernel(const float* __restrict__ x, const float* __restrict__ W,
                       float* __restrict__ outb, uint4* __restrict__ fh,
                       float4* __restrict__ xsq4)
{
    int n = blockIdx.x * 256 + threadIdx.x;
    float4 v0 = *reinterpret_cast<const float4*>(x + n * 8);
    float4 v1 = *reinterpret_cast<const float4*>(x + n * 8 + 4);
    float f[D] = {v0.x, v0.y, v0.z, v0.w, v1.x, v1.y, v1.z};
    float sq = 0.f;
#pragma unroll
    for (int c = 0; c < D; ++c) sq += f[c] * f[c];
    uint4 h;
    h.x = pkh(f[0], f[1]); h.y = pkh(f[2], f[3]);
    h.z = pkh(f[4], f[5]); h.w = pkh(f[6], sq);
    fh[n] = h;
    xsq4[n * 2]     = v0;
    xsq4[n * 2 + 1] = make_float4(v1.x, v1.y, v1.z, sq);
#pragma unroll
    for (int r = 0; r < D; ++r) {
        float acc = 0.f;
#pragma unroll
        for (int c = 0; c < D; ++c) acc += f[c] * W[r * D + c];
        acc = fminf(fmaxf(acc, -1.f), 1.f);
        outb[n * D + r] = acc;
    }
}

// ---------------------------------------------------------------------------
// Kernel 2 (R12-proven monolith): QB=16 MFMA screen. Half-sample pass-1 ->
// 34th-of-128 slot-min threshold -> full MFMA extraction (T+2d) -> exact
// fp32 prune (T+d) -> rank. NEW: wave-private u64-bisect fallback (R15-proven)
// replaces the block-wide sequential extractor.
// ---------------------------------------------------------------------------
__global__ __launch_bounds__(NT, 2)
void gat_kernel(const float* __restrict__ x, const float* __restrict__ aw,
                const float* __restrict__ outb, const uint4* __restrict__ fh,
                const float4* __restrict__ xs4, float* __restrict__ dout)
{
    __shared__ u64      cand[QB][ECAP2];      // 32 KB (aliases Lmin[128][16])
    __shared__ unsigned short ent[QB][SCAP];  // 10 KB
    __shared__ int      nbr[QB][K];           // 2 KB
    __shared__ uint4    qpk[QB];              // B-operand f16 rows
    __shared__ float4   qf4[QB][2];           // f32 query feats; [1].w = sqi
    __shared__ float    sqfL[QB];
    __shared__ unsigned selT[QB];
    __shared__ float    exqL[QB];             // exact prune threshold
    __shared__ float    scrL[QB];             // screen threshold
    __shared__ int      scnt[QB];
    __shared__ int      cnt2[QB];

    float* Lmin = (float*)cand;               // [128 slots][16 cols] f32, 8 KB

    const int tid  = threadIdx.x;
    const int lane = tid & 63;
    const int wave = tid >> 6;
    const int i0   = blockIdx.x * QB;
    const int col  = lane & 15;
    const int lg   = lane >> 4;

    if (tid < QB) {
        float4 b0 = xs4[(i0 + tid) * 2];
        float4 b1 = xs4[(i0 + tid) * 2 + 1];  // .w = sq_i
        qpk[tid] = make_uint4(pkh(-2.f * b0.x, -2.f * b0.y),
                              pkh(-2.f * b0.z, -2.f * b0.w),
                              pkh(-2.f * b1.x, -2.f * b1.y),
                              pkh(-2.f * b1.z, 1.0f));
        qf4[tid][0] = b0;
        qf4[tid][1] = b1;
        sqfL[tid]   = b1.w;
        scnt[tid] = 0;
        cnt2[tid] = 0;
    }
    __syncthreads();

    // B fragment: lane l<16 holds B[k=0..7][col=l] = [-2f_col(0..6), 1]
    U4H8 ub; ub.u = (lane < QB) ? qpk[lane] : make_uint4(0u, 0u, 0u, 0u);
    const f16x8 bfrag = ub.h;
    const f32x4 z4 = {0.f, 0.f, 0.f, 0.f};
    const int tb = wave * TPW;                // wave's 64-tile stripe

    // ---- pass 1: HALF-SAMPLE MFMA screen (32 tiles), 4 slot-mins/lane ----
    float lm0 = INFINITY, lm1 = INFINITY, lm2 = INFINITY, lm3 = INFINITY;
#pragma unroll 4
    for (int tt = 0; tt < TPW / 2; ++tt) {
        int t = tb + tt;
        uint4 au = make_uint4(0u, 0u, 0u, 0u);
        if (lane < 16) au = fh[t * 16 + lane];     // A[row=lane][k=0..7]
        U4H8 ua; ua.u = au;
        f32x4 acc = __builtin_amdgcn_mfma_f32_16x16x32_f16(ua.h, bfrag, z4, 0, 0, 0);
        lm0 = fminf(lm0, acc[0]);
        lm1 = fminf(lm1, acc[1]);
        lm2 = fminf(lm2, acc[2]);
        lm3 = fminf(lm3, acc[3]);
    }
    {   // slot = wave*16 + lg*4 + r; slots cover pairwise-disjoint j-sets
        int sb = wave * 16 + lg * 4;
        Lmin[(sb + 0) * 16 + col] = lm0;
        Lmin[(sb + 1) * 16 + col] = lm1;
        Lmin[(sb + 2) * 16 + col] = lm2;
        Lmin[(sb + 3) * 16 + col] = lm3;
    }
    __syncthreads();

    // ---- EXACT 34th-smallest of 128 slot-mins; wave w -> queries w, w+8 ----
    // >=34 disjoint slots <= T -> >=34 distinct j (>=33 non-diag) screen <= T
    // -> exact 32nd <= T+DELTA; top-32 member's screen <= T+2*DELTA.
#pragma unroll
    for (int h = 0; h < 2; ++h) {
        const int q = wave + h * 8;
        unsigned ov0 = ordu(Lmin[lane * 16 + q]);
        unsigned ov1 = ordu(Lmin[(64 + lane) * 16 + q]);
        unsigned lo = 0u, hi = 0xFFFFFFFFu;
        while (lo < hi) {
            unsigned mid = lo + ((hi - lo) >> 1);
            int cnt = __popcll(__ballot(ov0 <= mid))
                    + __popcll(__ballot(ov1 <= mid));
            if (cnt >= 34) hi = mid; else lo = mid + 1;
        }
        if (lane == 0) selT[q] = lo;
    }
    __syncthreads();

    if (tid < QB) {
        float Ts  = unordu(selT[tid]);
        float sq_ = sqfL[tid];
        exqL[tid] = fmaxf(Ts + DELTA, -sq_);               // exact keep
        scrL[tid] = fmaxf(Ts + 2.f * DELTA, -sq_ + DELTA); // screen keep
    }
    __syncthreads();

    // ---- pass 2: FULL MFMA extraction with min4 fast-path ----
    {
        float myscr = scrL[col];
#pragma unroll 4
        for (int tt = 0; tt < TPW; ++tt) {
            int t = tb + tt;
            uint4 au = make_uint4(0u, 0u, 0u, 0u);
            if (lane < 16) au = fh[t * 16 + lane];
            U4H8 ua; ua.u = au;
            f32x4 acc = __builtin_amdgcn_mfma_f32_16x16x32_f16(ua.h, bfrag, z4, 0, 0, 0);
            float v01 = fminf(acc[0], acc[1]);
            float v23 = fminf(acc[2], acc[3]);
            if (fminf(v01, v23) <= myscr) {
#pragma unroll
                for (int r = 0; r < 4; ++r) {
                    if (acc[r] <= myscr) {
                        int j = t * 16 + lg * 4 + r;
                        int p = atomicAdd(&scnt[col], 1);
                        if (p < SCAP) ent[col][p] = (unsigned short)j;
                    }
                }
            }
        }
    }
    __syncthreads();   // Lmin dead; cand may be overwritten now

    // ---- exact fp32 phase over survivors, prune at exqL -> rank keys ----
#pragma unroll 1
    for (int q = 0; q < QB; ++q) {
        int n = scnt[q];
        if (n > SCAP) n = SCAP;
        float4 A  = qf4[q][0];
        float4 Bv = qf4[q][1];                // .w = sqi
        float thr = exqL[q];
        for (int t = tid; t < n; t += NT) {
            int j = ent[q][t];
            float4 b0 = xs4[j * 2];
            float4 b1 = xs4[j * 2 + 1];       // .w = sq_j
            float m = dist_m(b0, b1, b1.w, A, Bv);
            if (m <= thr && j != i0 + q) {
                float d2c = fmaxf(Bv.w + m, 0.f);
                u64 key = ((u64)__float_as_uint(d2c) << 32) | (unsigned)j;
                int p = atomicAdd(&cnt2[q], 1);
                if (p < ECAP2) cand[q][p] = key;
            }
        }
    }
    __syncthreads();

    // ---- selection: wave w -> queries w, w+8 ----
    // OK path: rank the pruned keys. BAD path: wave-private u64-bisect exact
    // fallback (R15-proven on all queries) rebuilds cand[q], no barriers.
#pragma unroll 1
    for (int h = 0; h < 2; ++h) {
        const int q  = wave + h * 8;
        const int iq = i0 + q;
        int M = cnt2[q];                      // wave-uniform (LDS scalar)
        bool ok = (scnt[q] <= SCAP && M >= K && M <= ECAP2);
        if (!ok) {
            float4 A  = qf4[q][0];
            float4 Bv = qf4[q][1];
            u64 mink = ~0ull;
#pragma unroll 2
            for (int c = 0; c < 128; ++c) {
                int j = c * 64 + lane;
                float4 b0 = xs4[j * 2], b1 = xs4[j * 2 + 1];
                float m = dist_m(b0, b1, b1.w, A, Bv);
                float d2c = fmaxf(Bv.w + m, 0.f);
                u64 key = ((u64)__float_as_uint(d2c) << 32) | (unsigned)j;
                if (j != iq) mink = (key < mink) ? key : mink;
            }
            u64 lo = 0ull, hi = ~0ull;
            while (lo < hi) {                 // exact 33rd of 64 lane-mins
                u64 mid = lo + ((hi - lo) >> 1);
                int c = __popcll(__ballot(mink <= mid));
                if (c >= 33) hi = mid; else lo = mid + 1;
            }
            int base = 0;
#pragma unroll 2
            for (int c = 0; c < 128; ++c) {
                int j = c * 64 + lane;
                float4 b0 = xs4[j * 2], b1 = xs4[j * 2 + 1];
                float m = dist_m(b0, b1, b1.w, A, Bv);
                float d2c = fmaxf(Bv.w + m, 0.f);
                u64 key = ((u64)__float_as_uint(d2c) << 32) | (unsigned)j;
                bool in = (j != iq) && (key <= lo);
                u64 mk = __ballot(in);
                int px = __popcll(mk & ((1ull << lane) - 1ull));
                if (in && base + px < ECAP2) cand[q][base + px] = key;
                base += (int)__popcll(mk);
            }
            M = (base > ECAP2) ? ECAP2 : base;
        }
        // rank-by-count (keys unique; ascending (d2c, j) == jax order)
        for (int p = lane; p < M; p += 64) {
            u64 my = cand[q][p];
            int rank = 0;
            for (int m = 0; m < M; ++m)
                rank += (cand[q][m] < my) ? 1 : 0;
            if (rank < K) nbr[q][rank] = (int)(my & 0xffffffffu);
        }
    }
    __syncthreads();

    // ---- attention epilogue: wave w -> queries w, w+8; lanes 0..31 ----
#pragma unroll 1
    for (int h = 0; h < 2; ++h) {
        const int q  = wave + h * 8;
        const int iq = i0 + q;
        if (lane < K) {
            int nk = nbr[q][lane];
            float s = 0.f;
#pragma unroll
            for (int c = 0; c < D; ++c) s += outb[iq * D + c] * aw[c];
            float xp[D + 1];
#pragma unroll
            for (int c = 0; c < D; ++c) {
                float on = outb[nk * D + c];
                xp[c] = on;
                s += on * aw[D + c];
            }
            xp[D] = x[nk * 8 + 7];

            float m = s;
#pragma unroll
            for (int off = 16; off > 0; off >>= 1) m = fmaxf(m, __shfl_xor(m, off, 32));
            float e = expf(s - m);
            float sum = e;
#pragma unroll
            for (int off = 16; off > 0; off >>= 1) sum += __shfl_xor(sum, off, 32);
            float att = e / sum;

            float agg[D + 1];
#pragma unroll
            for (int dd = 0; dd < D + 1; ++dd) {
                float v = att * xp[dd];
#pragma unroll
                for (int off = 16; off > 0; off >>= 1) v += __shfl_xor(v, off, 32);
                agg[dd] = v;
            }

            if (lane < D) {
                float o = outb[iq * D + lane];
                dout[iq * 15 + lane] = o;
                dout[N_NODES * 15 + iq * 15 + lane] = o;
            }
            if (lane < D + 1) {
                float av_ = agg[0];
#pragma unroll
                for (int dd = 1; dd < D + 1; ++dd) av_ = (lane == dd) ? agg[dd] : av_;
                dout[iq * 15 + D + lane] = av_;
                dout[N_NODES * 15 + iq * 15 + D + lane] = av_;
            }
            if (iq == N_NODES - 1) dout[2 * N_NODES * 15 + lane] = att;
        }
    }
}

extern "C" void kernel_launch(void* const* d_in, const int* in_sizes, int n_in,
                              void* d_out, int out_size, void* d_ws, size_t ws_size,
                              hipStream_t stream) {
    (void)in_sizes; (void)n_in; (void)out_size; (void)ws_size;
    const float* x = (const float*)d_in[0];
    const float* W = (const float*)d_in[1];
    const float* a = (const float*)d_in[2];
    float* out   = (float*)d_out;
    float* outb  = (float*)d_ws;                      // 8192*7 f32 (224 KB)
    uint4* fh    = (uint4*)(outb + N_NODES * D);      // 8192*16 B (128 KB)
    float4* xsq4 = (float4*)(fh + N_NODES);           // 8192*32 B (256 KB)

    hipLaunchKernelGGL(precompute_kernel, dim3(N_NODES / 256), dim3(256),
                       0, stream, x, W, outb, fh, xsq4);
    hipLaunchKernelGGL(gat_kernel, dim3(N_NODES / QB), dim3(NT),
                       0, stream, x, a, outb, fh, xsq4, out);
}